// Round 13
// baseline (1822.424 us; speedup 1.0000x reference)
//
#include <hip/hip_runtime.h>
#include <hip/hip_bf16.h>

#define T_TOK 8192
#define HID 2048
#define FFN_ 8192
#define NE 8
#define MAXR 18432   // 16384 + 8*256 padding (segments 256-aligned)

typedef __attribute__((ext_vector_type(8))) short bf16x8;
typedef __attribute__((ext_vector_type(4))) float f32x4;
typedef __attribute__((ext_vector_type(8))) unsigned short u16x8;

__device__ __forceinline__ unsigned short f2bf(float f) {
  unsigned int u = __float_as_uint(f);
  u += 0x7fffu + ((u >> 16) & 1u);   // RNE
  return (unsigned short)(u >> 16);
}
__device__ __forceinline__ float bf2f(unsigned short h) {
  return __uint_as_float(((unsigned int)h) << 16);
}

__device__ __forceinline__ void gload_lds16(const ushort* g, ushort* l) {
  __builtin_amdgcn_global_load_lds(
      (const __attribute__((address_space(1))) unsigned int*)g,
      (__attribute__((address_space(3))) unsigned int*)l, 16, 0, 0);
}

// fast GELU (tanh form, max dev from erf-GELU ~3e-3 << bf16 noise)
__device__ __forceinline__ float gelu_f(float v) {
  float u = v * (0.7978845608f + 0.0356774081f * v * v);
  float a = fabsf(u);
  float ex = __expf(-2.f * a);
  float r = 1.f / (1.f + ex);
  float th = (1.f - ex) * r;
  th = (u >= 0.f) ? th : -th;
  return 0.5f * v * (1.f + th);
}

// ---------------- router: one wave per token ----------------
__global__ __launch_bounds__(256) void router_kernel(
    const float* __restrict__ x, const float* __restrict__ gw,
    int* __restrict__ topk_idx, float* __restrict__ topk_w, int* __restrict__ counts)
{
  int lane = threadIdx.x & 63;
  int w = threadIdx.x >> 6;
  int t = blockIdx.x * 4 + w;
  const float* xr = x + (size_t)t * HID;
  float acc[NE];
#pragma unroll
  for (int e = 0; e < NE; ++e) acc[e] = 0.f;
  for (int h = lane; h < HID; h += 64) {
    float xv = xr[h];
#pragma unroll
    for (int e = 0; e < NE; ++e) acc[e] = fmaf(xv, gw[e * HID + h], acc[e]);
  }
#pragma unroll
  for (int e = 0; e < NE; ++e) {
#pragma unroll
    for (int s = 32; s > 0; s >>= 1) acc[e] += __shfl_xor(acc[e], s);
  }
  if (lane == 0) {
    int i0 = 0; float v0 = acc[0];
#pragma unroll
    for (int e = 1; e < NE; ++e) { if (acc[e] > v0) { v0 = acc[e]; i0 = e; } }
    int i1 = -1; float v1 = -3.4e38f;
#pragma unroll
    for (int e = 0; e < NE; ++e) { if (e != i0 && acc[e] > v1) { v1 = acc[e]; i1 = e; } }
    float r = __expf(v1 - v0);
    float w0 = 1.f / (1.f + r);
    float w1 = r * w0;
    topk_idx[2 * t] = i0; topk_idx[2 * t + 1] = i1;
    topk_w[2 * t] = w0;   topk_w[2 * t + 1] = w1;
    atomicAdd(&counts[i0], 1);
    atomicAdd(&counts[i1], 1);
  }
}

__global__ void offsets_kernel(const int* __restrict__ counts, int* __restrict__ offs) {
  if (threadIdx.x == 0 && blockIdx.x == 0) {
    int o = 0;
#pragma unroll
    for (int e = 0; e < NE; ++e) { offs[e] = o; o += (counts[e] + 255) & ~255; }
    offs[NE] = o;
  }
}

__global__ __launch_bounds__(256) void scatter_kernel(
    const int* __restrict__ topk_idx, const float* __restrict__ topk_w,
    const int* __restrict__ offs, int* __restrict__ cursors,
    int* __restrict__ slot_token, float* __restrict__ slot_w, int* __restrict__ token_slot)
{
  int t = blockIdx.x * blockDim.x + threadIdx.x;
  if (t >= T_TOK) return;
#pragma unroll
  for (int k = 0; k < 2; ++k) {
    int e = topk_idx[2 * t + k];
    int pos = atomicAdd(&cursors[e], 1);
    int slot = offs[e] + pos;
    slot_token[slot] = t;
    slot_w[slot] = topk_w[2 * t + k];
    token_slot[2 * t + k] = slot;
  }
}

// ---------- fast fp32 [E][R][C] -> bf16 [E][C][R] : 64x512 strips, 16B stores ----------
__device__ __forceinline__ void wconv_body(
    ushort* ldsbuf, const float* __restrict__ src0, ushort* __restrict__ dst0,
    int R, int C, int b)
{
  ushort (*tile)[524] = (ushort (*)[524])ldsbuf;
  const int spr = C >> 9;              // 512-col strips per row-band
  const int spe = (R >> 6) * spr;      // strips per expert
  const int e = b / spe;
  const int s = b - e * spe;
  const int r0 = (s / spr) << 6;
  const int c0 = (s - (s / spr) * spr) << 9;
  const float* src = src0 + (size_t)e * R * C;
  ushort* dst = dst0 + (size_t)e * R * C;
  const int t = threadIdx.x;

#pragma unroll
  for (int i = 0; i < 16; ++i) {
    int idx = (i << 9) + t;
    int row = idx >> 7;
    int c4 = (idx & 127) << 2;
    float4 v = *(const float4*)&src[(size_t)(r0 + row) * C + c0 + c4];
    ushort4 u;
    u.x = f2bf(v.x); u.y = f2bf(v.y); u.z = f2bf(v.z); u.w = f2bf(v.w);
    *(ushort4*)&tile[row][c4] = u;
  }
  __syncthreads();
#pragma unroll
  for (int i = 0; i < 8; ++i) {
    int idx = (i << 9) + t;
    int c = idx >> 3;
    int r8 = (idx & 7) << 3;
    u16x8 o;
#pragma unroll
    for (int j = 0; j < 8; ++j) o[j] = tile[r8 + j][c];
    *(u16x8*)&dst[(size_t)(c0 + c) * R + r0 + r8] = o;
  }
}

__global__ __launch_bounds__(512) void wconvert_kernel(
    const float* __restrict__ src0, ushort* __restrict__ dst0, int R, int C)
{
  __shared__ ushort lds[64 * 524];
  wconv_body(lds, src0, dst0, R, C, blockIdx.x);
}

// gather 2 token rows per 512-thr block (co-launch form)
__device__ __forceinline__ void gather_body(
    const float* __restrict__ x, const int* __restrict__ slot_token,
    ushort* __restrict__ Xg, int b)
{
  int row = b * 2 + (threadIdx.x >> 8);
  int tok = slot_token[row];
  int c = (threadIdx.x & 255) * 8;
  ushort* dst = Xg + (size_t)row * HID + c;
  if (tok < 0) {
    u16x8 z = {0, 0, 0, 0, 0, 0, 0, 0};
    *(u16x8*)dst = z;
  } else {
    const float* s = x + (size_t)tok * HID + c;
    float4 a = *(const float4*)s;
    float4 bb = *(const float4*)(s + 4);
    u16x8 v;
    v[0] = f2bf(a.x); v[1] = f2bf(a.y); v[2] = f2bf(a.z); v[3] = f2bf(a.w);
    v[4] = f2bf(bb.x); v[5] = f2bf(bb.y); v[6] = f2bf(bb.z); v[7] = f2bf(bb.w);
    *(u16x8*)dst = v;
  }
}

__global__ __launch_bounds__(512) void gather_kernel512(
    const float* __restrict__ x, const int* __restrict__ slot_token, ushort* __restrict__ Xg)
{
  gather_body(x, slot_token, Xg, blockIdx.x);
}

// fused: w1 convert (blocks [0,convBlocks)) + gather (rest). Independent ops;
// conv is the long pole so its blocks lead in ID space.
__global__ __launch_bounds__(512) void gather_conv_kernel(
    const float* __restrict__ w1, ushort* __restrict__ w1t,
    const float* __restrict__ x, const int* __restrict__ slot_token,
    ushort* __restrict__ Xg, int convBlocks)
{
  __shared__ ushort lds[64 * 524];
  int b = blockIdx.x;
  if (b < convBlocks)
    wconv_body(lds, w1, w1t, HID, FFN_, b);
  else
    gather_body(x, slot_token, Xg, b - convBlocks);
}

// ============ GEMM TMx256, BK=64, 8 waves, 8-phase / 4-barrier, compiler-scheduled ======
// (r11 verbatim; __device__ body so it can be co-launched with wconvert blocks.)

#define VMWG() do { if constexpr (TM == 256) asm volatile("s_waitcnt vmcnt(6)" ::: "memory"); \
                    else                     asm volatile("s_waitcnt vmcnt(5)" ::: "memory"); } while (0)
#define VMW0() do { asm volatile("s_waitcnt vmcnt(0)" ::: "memory"); } while (0)
#define SCB()  __builtin_amdgcn_sched_barrier(0)
#define BAR()  __builtin_amdgcn_s_barrier()

#define STG_A(BUF, HALF, T) do {                                            \
    ushort* _d = lds + (BUF) * BUFS + (HALF) * REGA + tid * 8;              \
    gload_lds16(sA0 + (size_t)(HALF) * HOFFA + (size_t)(T) * 64, _d);       \
    if constexpr (TM == 256)                                                \
      gload_lds16(sA1 + (size_t)(HALF) * HOFFA + (size_t)(T) * 64, _d + 4096); \
  } while (0)
#define STG_B(BUF, HALF, T) do {                                            \
    ushort* _d = lds + (BUF) * BUFS + 2 * REGA + (HALF) * 8192 + tid * 8;   \
    gload_lds16(sB0 + (size_t)(HALF) * 32 * K + (size_t)(T) * 64, _d);      \
    gload_lds16(sB1 + (size_t)(HALF) * 32 * K + (size_t)(T) * 64, _d + 4096); \
  } while (0)

#define LDA(BUF, MQ) do {                                                   \
    _Pragma("unroll") for (int mm = 0; mm < MA; ++mm) {                     \
      const ushort* _p = lds + (BUF) * BUFS + (MQ) * REGA + aoff + mm * 1024; \
      af[mm][0] = *(const bf16x8*)(_p + ck0);                               \
      af[mm][1] = *(const bf16x8*)(_p + ck1);                               \
    } } while (0)
#define LDB(BUF, NQ) do {                                                   \
    _Pragma("unroll") for (int nn = 0; nn < 2; ++nn) {                      \
      const ushort* _p = lds + (BUF) * BUFS + 2 * REGA + (NQ) * 8192 + boff + nn * 1024; \
      bf[NQ][nn][0] = *(const bf16x8*)(_p + ck0);                           \
      bf[NQ][nn][1] = *(const bf16x8*)(_p + ck1);                           \
    } } while (0)

#define MM(MQ, NQ) do {                                                     \
    __builtin_amdgcn_s_setprio(1);                                          \
    _Pragma("unroll") for (int mm = 0; mm < MA; ++mm)                       \
    _Pragma("unroll") for (int nn = 0; nn < 2; ++nn) {                      \
      acc[(MQ)*MA+mm][(NQ)*2+nn] = __builtin_amdgcn_mfma_f32_16x16x32_bf16( \
          af[mm][0], bf[NQ][nn][0], acc[(MQ)*MA+mm][(NQ)*2+nn], 0, 0, 0);   \
      acc[(MQ)*MA+mm][(NQ)*2+nn] = __builtin_amdgcn_mfma_f32_16x16x32_bf16( \
          af[mm][1], bf[NQ][nn][1], acc[(MQ)*MA+mm][(NQ)*2+nn], 0, 0, 0);   \
    }                                                                       \
    __builtin_amdgcn_s_setprio(0);                                          \
  } while (0)

template <int EPI, int TM>
__device__ __forceinline__ void gemm_body(
    ushort* lds,
    const ushort* __restrict__ A, const ushort* __restrict__ Bt,
    const float* __restrict__ bias, ushort* __restrict__ Cout,
    const float* __restrict__ slot_w, const int* __restrict__ offs,
    int K, int N, int gy, int nwg, int bidx)
{
  constexpr int REGA = TM * 32;          // A region ushorts (half the A tile)
  constexpr int BUFS = 2 * REGA + 16384; // buffer stride ushorts
  constexpr int MA = TM / 64;            // A frags per region per wave
  constexpr int HOFFA_ROWS = TM / 4;     // A half offset in global rows (64 or 32)

  const int tid = threadIdx.x;
  const size_t HOFFA = (size_t)HOFFA_ROWS * K;
  // XCD-chunked swizzle + column-major decode within chunk (r5/r6, proven).
  int wg = bidx;
  int cpx = nwg >> 3;
  wg = (wg & 7) * cpx + (wg >> 3);
  int cb = wg / gy;
  int rb = wg - cb * gy;

  int total = offs[NE];
  int row0 = rb * TM;
  if (row0 >= total) return;
  int e = 0;
#pragma unroll
  for (int i = 1; i < NE; ++i) e += (row0 >= offs[i]) ? 1 : 0;

  const ushort* Ag = A + (size_t)row0 * K;
  const ushort* Bg = Bt + ((size_t)e * N + (size_t)cb * 256) * K;

  // staging source (pre-swizzled); LDS dest linear
  const int pr0 = tid >> 3;                     // 0..63
  const int pr1 = 64 + pr0;
  const int j0 = (tid & 7) ^ (pr0 & 7);
  const int j1 = (tid & 7) ^ (pr1 & 7);
  const int rA0 = (TM == 256) ? pr0 : (((pr0 >> 5) << 6) + (pr0 & 31));
  const int rA1 = 128 + pr0;                    // only used when TM==256
  const int rB0 = ((pr0 >> 5) << 6) + (pr0 & 31);   // B map: (p>>5)*64 + (p&31)
  const int rB1 = ((pr1 >> 5) << 6) + (pr1 & 31);
  const ushort* sA0 = Ag + (size_t)rA0 * K + j0 * 8;
  const ushort* sA1 = Ag + (size_t)rA1 * K + j1 * 8;
  const ushort* sB0 = Bg + (size_t)rB0 * K + j0 * 8;
  const ushort* sB1 = Bg + (size_t)rB1 * K + j1 * 8;

  // fragment read addressing
  const int lane = tid & 63;
  const int wid = tid >> 6;
  const int wr = wid >> 2, wc = wid & 3;    // wave grid 2(M) x 4(N)
  const int lrow = lane & 15, g = lane >> 4, x7 = lrow & 7;
  const int ck0 = (g ^ x7) * 8;
  const int ck1 = ((4 + g) ^ x7) * 8;
  const int aoff = (wr * (TM / 4) + lrow) * 64;
  const int boff = (wc * 32 + lrow) * 64;

  f32x4 acc[TM / 32][4] = {};
  bf16x8 af[MA][2], bf[2][2][2];

  const int NT = K >> 6;
  const int NITER = NT >> 1;

  // prologue: tile0 full + tile1 {A_first,B_first,B_second}; wait tile0 landed
  STG_A(0, 0, 0); STG_A(0, 1, 0); STG_B(0, 0, 0); STG_B(0, 1, 0);
  STG_A(1, 0, 1); STG_B(1, 0, 1); STG_B(1, 1, 1);
  VMWG();
  BAR(); SCB();

  for (int it = 0; it < NITER; ++it) {
    const int tb = 2 * it + 1;
    const int tn0 = 2 * it + 2;
    const int tn1 = 2 * it + 3;
    const bool more0 = tn0 < NT;
    const bool more1 = tn1 < NT;
    const bool last = (it + 1 == NITER);

    // ===== group 1: ph1, ph2 =====
    STG_A(1, 1, tb);
    LDA(0, 0); LDB(0, 0);
    LDB(0, 1);
    MM(0, 0);
    MM(0, 1);
    BAR(); SCB();                // B1

    // ===== group 2: ph3, ph4 =====
    if (more0) { STG_A(0, 0, tn0); STG_B(0, 0, tn0); }
    LDA(0, 1);
    MM(1, 0);
    if (more0) STG_B(0, 1, tn0);
    MM(1, 1);
    if (last) { VMW0(); } else { VMWG(); }
    BAR(); SCB();                // B2

    // ===== group 3: ph5, ph6 =====
    if (more0) STG_A(0, 1, tn0);
    LDA(1, 0); LDB(1, 0);
    LDB(1, 1);
    MM(0, 0);
    MM(0, 1);
    BAR(); SCB();                // B3

    // ===== group 4: ph7, ph8 =====
    if (more1) { STG_A(1, 0, tn1); STG_B(1, 0, tn1); }
    LDA(1, 1);
    MM(1, 0);
    if (more1) STG_B(1, 1, tn1);
    MM(1, 1);
    if (more1) VMWG();
    BAR(); SCB();                // B4
  }

  // epilogue: m-outer, i-mid, n-inner (4 stores per 128B output line back-to-back)
  const int colb = cb * 256 + wc * 64;
  const int rowb = row0 + wr * (TM / 2);
  float bv[4];
#pragma unroll
  for (int n = 0; n < 4; ++n)
    bv[n] = bias[(size_t)e * N + colb + n * 16 + lrow];
#pragma unroll
  for (int m = 0; m < TM / 32; ++m) {
    const int mq = m / MA, mm = m % MA;
    const int gr = rowb + mq * (TM / 4) + mm * 16 + g * 4;
#pragma unroll
    for (int i = 0; i < 4; ++i) {
      const int grow = gr + i;
      float sw = (EPI == 1) ? slot_w[grow] : 0.f;
      ushort* crow = Cout + (size_t)grow * N + colb + lrow;
#pragma unroll
      for (int n = 0; n < 4; ++n) {
        float v = acc[m][n][i] + bv[n];
        if (EPI == 0) v = gelu_f(v);
        else          v *= sw;
        crow[n * 16] = f2bf(v);
      }
    }
  }
}

template <int EPI, int TM>
__global__ __launch_bounds__(512, 2) void gemm256_kernel(
    const ushort* __restrict__ A, const ushort* __restrict__ Bt,
    const float* __restrict__ bias, ushort* __restrict__ Cout,
    const float* __restrict__ slot_w, const int* __restrict__ offs,
    int K, int N, int gy)
{
  __shared__ ushort lds[TM * 128 + 32768];   // 128 KiB (TM=256) / 96 KiB (TM=128)
  gemm_body<EPI, TM>(lds, A, Bt, bias, Cout, slot_w, offs, K, N, gy,
                     (int)gridDim.x, (int)blockIdx.x);
}

// fused: gemm1 (blocks [0,gemmBlocks)) + w2 transpose-convert (rest).
// Valid only when w2t does NOT alias w1t (separate workspace region).
__global__ __launch_bounds__(512, 2) void gemm1_conv_kernel(
    const ushort* __restrict__ A, const ushort* __restrict__ Bt,
    const float* __restrict__ bias, ushort* __restrict__ Cout,
    const int* __restrict__ offs,
    const float* __restrict__ w2, ushort* __restrict__ w2t, int gemmBlocks)
{
  __shared__ ushort lds[65536];
  if ((int)blockIdx.x < gemmBlocks)
    gemm_body<0, 256>(lds, A, Bt, bias, Cout, nullptr, offs, HID, FFN_,
                      MAXR / 256, gemmBlocks, (int)blockIdx.x);
  else
    wconv_body(lds, w2, w2t, FFN_, HID, (int)blockIdx.x - gemmBlocks);
}

// out = x + Y[slot0] + Y[slot1]
__global__ __launch_bounds__(256) void combine_kernel(
    const float* __restrict__ x, const ushort* __restrict__ Yp,
    const int* __restrict__ token_slot, float* __restrict__ out)
{
  int t = blockIdx.x;
  int s0 = token_slot[2 * t], s1 = token_slot[2 * t + 1];
  int c = threadIdx.x * 8;
  const float* xr = x + (size_t)t * HID + c;
  u16x8 y0 = *(const u16x8*)&Yp[(size_t)s0 * HID + c];
  u16x8 y1 = *(const u16x8*)&Yp[(size_t)s1 * HID + c];
  float4 xa = *(const float4*)xr;
  float4 xb = *(const float4*)(xr + 4);
  float4 oa, ob;
  oa.x = xa.x + bf2f(y0[0]) + bf2f(y1[0]);
  oa.y = xa.y + bf2f(y0[1]) + bf2f(y1[1]);
  oa.z = xa.z + bf2f(y0[2]) + bf2f(y1[2]);
  oa.w = xa.w + bf2f(y0[3]) + bf2f(y1[3]);
  ob.x = xb.x + bf2f(y0[4]) + bf2f(y1[4]);
  ob.y = xb.y + bf2f(y0[5]) + bf2f(y1[5]);
  ob.z = xb.z + bf2f(y0[6]) + bf2f(y1[6]);
  ob.w = xb.w + bf2f(y0[7]) + bf2f(y1[7]);
  float* orow = out + (size_t)t * HID + c;
  *(float4*)orow = oa;
  *(float4*)(orow + 4) = ob;
}

extern "C" void kernel_launch(void* const* d_in, const int* in_sizes, int n_in,
                              void* d_out, int out_size, void* d_ws, size_t ws_size,
                              hipStream_t stream)
{
  const float* x  = (const float*)d_in[0];
  const float* gw = (const float*)d_in[1];
  const float* w1 = (const float*)d_in[2];
  const float* b1 = (const float*)d_in[3];
  const float* w2 = (const float*)d_in[4];
  const float* b2 = (const float*)d_in[5];
  float* out = (float*)d_out;

  char* ws = (char*)d_ws;
  ushort* wT  = (ushort*)(ws + 0);            // w1t: [E][F][H] bf16, 268,435,456
  ushort* Hb  = (ushort*)(ws + 268435456);    // [MAXR][FFN] bf16: 301,989,888
  ushort* Xg  = (ushort*)(ws + 570425344);    // [MAXR][HID] bf16: 75,497,472
  ushort* Yp  = Xg;                           // Ypair overlays Xg
  char* sm = ws + 645922816;
  int*   slot_token = (int*)(sm);
  float* slot_w     = (float*)(sm + 73728);
  int*   token_slot = (int*)(sm + 147456);
  int*   topk_idx   = (int*)(sm + 212992);
  float* topk_w     = (float*)(sm + 278528);
  int*   counts     = (int*)(sm + 344064);
  int*   cursors    = (int*)(sm + 344096);
  int*   offs       = (int*)(sm + 344128);

  // fused-mode w2t region (separate from w1t) if workspace allows
  const size_t W2T_OFF = 646267136ULL;
  const bool fused = ws_size >= W2T_OFF + 268435456ULL;
  ushort* w2t = fused ? (ushort*)(ws + W2T_OFF) : wT;

  hipMemsetAsync(counts, 0, 64, stream);
  hipMemsetAsync(slot_token, 0xFF, MAXR * 4, stream);

  router_kernel<<<dim3(T_TOK / 4), dim3(256), 0, stream>>>(x, gw, topk_idx, topk_w, counts);
  offsets_kernel<<<dim3(1), dim3(64), 0, stream>>>(counts, offs);
  scatter_kernel<<<dim3(T_TOK / 256), dim3(256), 0, stream>>>(
      topk_idx, topk_w, offs, cursors, slot_token, slot_w, token_slot);

  // fused: w1 convert (4096 blocks, long pole, leads) + gather (9216 blocks, fills gaps)
  gather_conv_kernel<<<dim3(4096 + MAXR / 2), dim3(512), 0, stream>>>(
      w1, wT, x, slot_token, Xg, 4096);

  if (fused) {
    // gemm1 + w2 convert co-launched: convert blocks fill spare BW/CU slots
    gemm1_conv_kernel<<<dim3(2304 + 4096), dim3(512), 0, stream>>>(
        Xg, wT, b1, Hb, offs, w2, w2t, 2304);
  } else {
    gemm256_kernel<0, 256><<<dim3(2304), dim3(512), 0, stream>>>(
        Xg, wT, b1, Hb, nullptr, offs, HID, FFN_, MAXR / 256);
    wconvert_kernel<<<dim3(4096), dim3(512), 0, stream>>>(w2, wT, FFN_, HID);
  }

  // gemm2: TM=128 tiles -> 1152 blocks (4.5/CU)
  gemm256_kernel<1, 128><<<dim3(1152), dim3(512), 0, stream>>>(
      Hb, w2t, b2, Yp, slot_w, offs, FFN_, HID, MAXR / 128);

  combine_kernel<<<dim3(T_TOK), dim3(256), 0, stream>>>(x, Yp, token_slot, out);
}

// Round 14
// 1790.256 us; speedup vs baseline: 1.0180x; 1.0180x over previous
//
#include <hip/hip_runtime.h>
#include <hip/hip_bf16.h>

#define T_TOK 8192
#define HID 2048
#define FFN_ 8192
#define NE 8
#define MAXR 18432   // 16384 + 8*256 padding (segments 256-aligned)

typedef __attribute__((ext_vector_type(8))) short bf16x8;
typedef __attribute__((ext_vector_type(4))) float f32x4;
typedef __attribute__((ext_vector_type(8))) unsigned short u16x8;

__device__ __forceinline__ unsigned short f2bf(float f) {
  unsigned int u = __float_as_uint(f);
  u += 0x7fffu + ((u >> 16) & 1u);   // RNE
  return (unsigned short)(u >> 16);
}
__device__ __forceinline__ float bf2f(unsigned short h) {
  return __uint_as_float(((unsigned int)h) << 16);
}

__device__ __forceinline__ void gload_lds16(const ushort* g, ushort* l) {
  __builtin_amdgcn_global_load_lds(
      (const __attribute__((address_space(1))) unsigned int*)g,
      (__attribute__((address_space(3))) unsigned int*)l, 16, 0, 0);
}

// fast GELU (tanh form, max dev from erf-GELU ~3e-3 << bf16 noise)
__device__ __forceinline__ float gelu_f(float v) {
  float u = v * (0.7978845608f + 0.0356774081f * v * v);
  float a = fabsf(u);
  float ex = __expf(-2.f * a);
  float r = 1.f / (1.f + ex);
  float th = (1.f - ex) * r;
  th = (u >= 0.f) ? th : -th;
  return 0.5f * v * (1.f + th);
}

// ---------------- router: one wave per token ----------------
__global__ __launch_bounds__(256) void router_kernel(
    const float* __restrict__ x, const float* __restrict__ gw,
    int* __restrict__ topk_idx, float* __restrict__ topk_w, int* __restrict__ counts)
{
  int lane = threadIdx.x & 63;
  int w = threadIdx.x >> 6;
  int t = blockIdx.x * 4 + w;
  const float* xr = x + (size_t)t * HID;
  float acc[NE];
#pragma unroll
  for (int e = 0; e < NE; ++e) acc[e] = 0.f;
  for (int h = lane; h < HID; h += 64) {
    float xv = xr[h];
#pragma unroll
    for (int e = 0; e < NE; ++e) acc[e] = fmaf(xv, gw[e * HID + h], acc[e]);
  }
#pragma unroll
  for (int e = 0; e < NE; ++e) {
#pragma unroll
    for (int s = 32; s > 0; s >>= 1) acc[e] += __shfl_xor(acc[e], s);
  }
  if (lane == 0) {
    int i0 = 0; float v0 = acc[0];
#pragma unroll
    for (int e = 1; e < NE; ++e) { if (acc[e] > v0) { v0 = acc[e]; i0 = e; } }
    int i1 = -1; float v1 = -3.4e38f;
#pragma unroll
    for (int e = 0; e < NE; ++e) { if (e != i0 && acc[e] > v1) { v1 = acc[e]; i1 = e; } }
    float r = __expf(v1 - v0);
    float w0 = 1.f / (1.f + r);
    float w1 = r * w0;
    topk_idx[2 * t] = i0; topk_idx[2 * t + 1] = i1;
    topk_w[2 * t] = w0;   topk_w[2 * t + 1] = w1;
    atomicAdd(&counts[i0], 1);
    atomicAdd(&counts[i1], 1);
  }
}

__global__ void offsets_kernel(const int* __restrict__ counts, int* __restrict__ offs) {
  if (threadIdx.x == 0 && blockIdx.x == 0) {
    int o = 0;
#pragma unroll
    for (int e = 0; e < NE; ++e) { offs[e] = o; o += (counts[e] + 255) & ~255; }
    offs[NE] = o;
  }
}

__global__ __launch_bounds__(256) void scatter_kernel(
    const int* __restrict__ topk_idx, const float* __restrict__ topk_w,
    const int* __restrict__ offs, int* __restrict__ cursors,
    int* __restrict__ slot_token, float* __restrict__ slot_w, int* __restrict__ token_slot)
{
  int t = blockIdx.x * blockDim.x + threadIdx.x;
  if (t >= T_TOK) return;
#pragma unroll
  for (int k = 0; k < 2; ++k) {
    int e = topk_idx[2 * t + k];
    int pos = atomicAdd(&cursors[e], 1);
    int slot = offs[e] + pos;
    slot_token[slot] = t;
    slot_w[slot] = topk_w[2 * t + k];
    token_slot[2 * t + k] = slot;
  }
}

// ---------- fast fp32 [E][R][C] -> bf16 [E][C][R] : 64x512 strips, 16B stores ----------
__device__ __forceinline__ void wconv_body(
    ushort* ldsbuf, const float* __restrict__ src0, ushort* __restrict__ dst0,
    int R, int C, int b)
{
  ushort (*tile)[524] = (ushort (*)[524])ldsbuf;
  const int spr = C >> 9;              // 512-col strips per row-band
  const int spe = (R >> 6) * spr;      // strips per expert
  const int e = b / spe;
  const int s = b - e * spe;
  const int r0 = (s / spr) << 6;
  const int c0 = (s - (s / spr) * spr) << 9;
  const float* src = src0 + (size_t)e * R * C;
  ushort* dst = dst0 + (size_t)e * R * C;
  const int t = threadIdx.x;

#pragma unroll
  for (int i = 0; i < 16; ++i) {
    int idx = (i << 9) + t;
    int row = idx >> 7;
    int c4 = (idx & 127) << 2;
    float4 v = *(const float4*)&src[(size_t)(r0 + row) * C + c0 + c4];
    ushort4 u;
    u.x = f2bf(v.x); u.y = f2bf(v.y); u.z = f2bf(v.z); u.w = f2bf(v.w);
    *(ushort4*)&tile[row][c4] = u;
  }
  __syncthreads();
#pragma unroll
  for (int i = 0; i < 8; ++i) {
    int idx = (i << 9) + t;
    int c = idx >> 3;
    int r8 = (idx & 7) << 3;
    u16x8 o;
#pragma unroll
    for (int j = 0; j < 8; ++j) o[j] = tile[r8 + j][c];
    *(u16x8*)&dst[(size_t)(c0 + c) * R + r0 + r8] = o;
  }
}

__global__ __launch_bounds__(512) void wconvert_kernel(
    const float* __restrict__ src0, ushort* __restrict__ dst0, int R, int C)
{
  __shared__ ushort lds[64 * 524];
  wconv_body(lds, src0, dst0, R, C, blockIdx.x);
}

// gather 2 token rows per 512-thr block (co-launch form)
__device__ __forceinline__ void gather_body(
    const float* __restrict__ x, const int* __restrict__ slot_token,
    ushort* __restrict__ Xg, int b)
{
  int row = b * 2 + (threadIdx.x >> 8);
  int tok = slot_token[row];
  int c = (threadIdx.x & 255) * 8;
  ushort* dst = Xg + (size_t)row * HID + c;
  if (tok < 0) {
    u16x8 z = {0, 0, 0, 0, 0, 0, 0, 0};
    *(u16x8*)dst = z;
  } else {
    const float* s = x + (size_t)tok * HID + c;
    float4 a = *(const float4*)s;
    float4 bb = *(const float4*)(s + 4);
    u16x8 v;
    v[0] = f2bf(a.x); v[1] = f2bf(a.y); v[2] = f2bf(a.z); v[3] = f2bf(a.w);
    v[4] = f2bf(bb.x); v[5] = f2bf(bb.y); v[6] = f2bf(bb.z); v[7] = f2bf(bb.w);
    *(u16x8*)dst = v;
  }
}

// fused: w1 convert (blocks [0,convBlocks)) + gather (rest).
__global__ __launch_bounds__(512) void gather_conv_kernel(
    const float* __restrict__ w1, ushort* __restrict__ w1t,
    const float* __restrict__ x, const int* __restrict__ slot_token,
    ushort* __restrict__ Xg, int convBlocks)
{
  __shared__ ushort lds[64 * 524];
  int b = blockIdx.x;
  if (b < convBlocks)
    wconv_body(lds, w1, w1t, HID, FFN_, b);
  else
    gather_body(x, slot_token, Xg, b - convBlocks);
}

// ============ GEMM TMx256, BK=64, 8 waves, 8-phase / 4-barrier (r11, proven) ======

#define VMWG() do { if constexpr (TM == 256) asm volatile("s_waitcnt vmcnt(6)" ::: "memory"); \
                    else                     asm volatile("s_waitcnt vmcnt(5)" ::: "memory"); } while (0)
#define VMW0() do { asm volatile("s_waitcnt vmcnt(0)" ::: "memory"); } while (0)
#define VMW6() do { asm volatile("s_waitcnt vmcnt(6)" ::: "memory"); } while (0)
#define SCB()  __builtin_amdgcn_sched_barrier(0)
#define BAR()  __builtin_amdgcn_s_barrier()

#define STG_A(BUF, HALF, T) do {                                            \
    ushort* _d = lds + (BUF) * BUFS + (HALF) * REGA + tid * 8;              \
    gload_lds16(sA0 + (size_t)(HALF) * HOFFA + (size_t)(T) * 64, _d);       \
    if constexpr (TM == 256)                                                \
      gload_lds16(sA1 + (size_t)(HALF) * HOFFA + (size_t)(T) * 64, _d + 4096); \
  } while (0)
#define STG_B(BUF, HALF, T) do {                                            \
    ushort* _d = lds + (BUF) * BUFS + 2 * REGA + (HALF) * 8192 + tid * 8;   \
    gload_lds16(sB0 + (size_t)(HALF) * 32 * K + (size_t)(T) * 64, _d);      \
    gload_lds16(sB1 + (size_t)(HALF) * 32 * K + (size_t)(T) * 64, _d + 4096); \
  } while (0)

#define LDA(BUF, MQ) do {                                                   \
    _Pragma("unroll") for (int mm = 0; mm < MA; ++mm) {                     \
      const ushort* _p = lds + (BUF) * BUFS + (MQ) * REGA + aoff + mm * 1024; \
      af[mm][0] = *(const bf16x8*)(_p + ck0);                               \
      af[mm][1] = *(const bf16x8*)(_p + ck1);                               \
    } } while (0)
#define LDB(BUF, NQ) do {                                                   \
    _Pragma("unroll") for (int nn = 0; nn < 2; ++nn) {                      \
      const ushort* _p = lds + (BUF) * BUFS + 2 * REGA + (NQ) * 8192 + boff + nn * 1024; \
      bf[NQ][nn][0] = *(const bf16x8*)(_p + ck0);                           \
      bf[NQ][nn][1] = *(const bf16x8*)(_p + ck1);                           \
    } } while (0)

#define MM(MQ, NQ) do {                                                     \
    __builtin_amdgcn_s_setprio(1);                                          \
    _Pragma("unroll") for (int mm = 0; mm < MA; ++mm)                       \
    _Pragma("unroll") for (int nn = 0; nn < 2; ++nn) {                      \
      acc[(MQ)*MA+mm][(NQ)*2+nn] = __builtin_amdgcn_mfma_f32_16x16x32_bf16( \
          af[mm][0], bf[NQ][nn][0], acc[(MQ)*MA+mm][(NQ)*2+nn], 0, 0, 0);   \
      acc[(MQ)*MA+mm][(NQ)*2+nn] = __builtin_amdgcn_mfma_f32_16x16x32_bf16( \
          af[mm][1], bf[NQ][nn][1], acc[(MQ)*MA+mm][(NQ)*2+nn], 0, 0, 0);   \
    }                                                                       \
    __builtin_amdgcn_s_setprio(0);                                          \
  } while (0)

template <int EPI, int TM>
__device__ __forceinline__ void gemm_body(
    ushort* lds,
    const ushort* __restrict__ A, const ushort* __restrict__ Bt,
    const float* __restrict__ bias, ushort* __restrict__ Cout,
    const float* __restrict__ slot_w, const int* __restrict__ offs,
    int K, int N, int gy, int nwg, int bidx)
{
  constexpr int REGA = TM * 32;
  constexpr int BUFS = 2 * REGA + 16384;
  constexpr int MA = TM / 64;
  constexpr int HOFFA_ROWS = TM / 4;

  const int tid = threadIdx.x;
  const size_t HOFFA = (size_t)HOFFA_ROWS * K;
  int wg = bidx;
  int cpx = nwg >> 3;
  wg = (wg & 7) * cpx + (wg >> 3);
  int cb = wg / gy;
  int rb = wg - cb * gy;

  int total = offs[NE];
  int row0 = rb * TM;
  if (row0 >= total) return;
  int e = 0;
#pragma unroll
  for (int i = 1; i < NE; ++i) e += (row0 >= offs[i]) ? 1 : 0;

  const ushort* Ag = A + (size_t)row0 * K;
  const ushort* Bg = Bt + ((size_t)e * N + (size_t)cb * 256) * K;

  const int pr0 = tid >> 3;
  const int pr1 = 64 + pr0;
  const int j0 = (tid & 7) ^ (pr0 & 7);
  const int j1 = (tid & 7) ^ (pr1 & 7);
  const int rA0 = (TM == 256) ? pr0 : (((pr0 >> 5) << 6) + (pr0 & 31));
  const int rA1 = 128 + pr0;
  const int rB0 = ((pr0 >> 5) << 6) + (pr0 & 31);
  const int rB1 = ((pr1 >> 5) << 6) + (pr1 & 31);
  const ushort* sA0 = Ag + (size_t)rA0 * K + j0 * 8;
  const ushort* sA1 = Ag + (size_t)rA1 * K + j1 * 8;
  const ushort* sB0 = Bg + (size_t)rB0 * K + j0 * 8;
  const ushort* sB1 = Bg + (size_t)rB1 * K + j1 * 8;

  const int lane = tid & 63;
  const int wid = tid >> 6;
  const int wr = wid >> 2, wc = wid & 3;
  const int lrow = lane & 15, g = lane >> 4, x7 = lrow & 7;
  const int ck0 = (g ^ x7) * 8;
  const int ck1 = ((4 + g) ^ x7) * 8;
  const int aoff = (wr * (TM / 4) + lrow) * 64;
  const int boff = (wc * 32 + lrow) * 64;

  f32x4 acc[TM / 32][4] = {};
  bf16x8 af[MA][2], bf[2][2][2];

  const int NT = K >> 6;
  const int NITER = NT >> 1;

  STG_A(0, 0, 0); STG_A(0, 1, 0); STG_B(0, 0, 0); STG_B(0, 1, 0);
  STG_A(1, 0, 1); STG_B(1, 0, 1); STG_B(1, 1, 1);
  VMWG();
  BAR(); SCB();

  for (int it = 0; it < NITER; ++it) {
    const int tb = 2 * it + 1;
    const int tn0 = 2 * it + 2;
    const int tn1 = 2 * it + 3;
    const bool more0 = tn0 < NT;
    const bool more1 = tn1 < NT;
    const bool last = (it + 1 == NITER);

    STG_A(1, 1, tb);
    LDA(0, 0); LDB(0, 0);
    LDB(0, 1);
    MM(0, 0);
    MM(0, 1);
    BAR(); SCB();                // B1

    if (more0) { STG_A(0, 0, tn0); STG_B(0, 0, tn0); }
    LDA(0, 1);
    MM(1, 0);
    if (more0) STG_B(0, 1, tn0);
    MM(1, 1);
    if (last) { VMW0(); } else { VMWG(); }
    BAR(); SCB();                // B2

    if (more0) STG_A(0, 1, tn0);
    LDA(1, 0); LDB(1, 0);
    LDB(1, 1);
    MM(0, 0);
    MM(0, 1);
    BAR(); SCB();                // B3

    if (more1) { STG_A(1, 0, tn1); STG_B(1, 0, tn1); }
    LDA(1, 1);
    MM(1, 0);
    if (more1) STG_B(1, 1, tn1);
    MM(1, 1);
    if (more1) VMWG();
    BAR(); SCB();                // B4
  }

  const int colb = cb * 256 + wc * 64;
  const int rowb = row0 + wr * (TM / 2);
  float bv[4];
#pragma unroll
  for (int n = 0; n < 4; ++n)
    bv[n] = bias[(size_t)e * N + colb + n * 16 + lrow];
#pragma unroll
  for (int m = 0; m < TM / 32; ++m) {
    const int mq = m / MA, mm = m % MA;
    const int gr = rowb + mq * (TM / 4) + mm * 16 + g * 4;
#pragma unroll
    for (int i = 0; i < 4; ++i) {
      const int grow = gr + i;
      float sw = (EPI == 1) ? slot_w[grow] : 0.f;
      ushort* crow = Cout + (size_t)grow * N + colb + lrow;
#pragma unroll
      for (int n = 0; n < 4; ++n) {
        float v = acc[m][n][i] + bv[n];
        if (EPI == 0) v = gelu_f(v);
        else          v *= sw;
        crow[n * 16] = f2bf(v);
      }
    }
  }
}

template <int EPI, int TM>
__global__ __launch_bounds__(512, 2) void gemm256_kernel(
    const ushort* __restrict__ A, const ushort* __restrict__ Bt,
    const float* __restrict__ bias, ushort* __restrict__ Cout,
    const float* __restrict__ slot_w, const int* __restrict__ offs,
    int K, int N, int gy)
{
  __shared__ ushort lds[TM * 128 + 32768];
  gemm_body<EPI, TM>(lds, A, Bt, bias, Cout, slot_w, offs, K, N, gy,
                     (int)gridDim.x, (int)blockIdx.x);
}

// fused: gemm1 (blocks [0,gemmBlocks)) + w2 transpose-convert (rest).
__global__ __launch_bounds__(512, 2) void gemm1_conv_kernel(
    const ushort* __restrict__ A, const ushort* __restrict__ Bt,
    const float* __restrict__ bias, ushort* __restrict__ Cout,
    const int* __restrict__ offs,
    const float* __restrict__ w2, ushort* __restrict__ w2t, int gemmBlocks)
{
  __shared__ ushort lds[65536];
  if ((int)blockIdx.x < gemmBlocks)
    gemm_body<0, 256>(lds, A, Bt, bias, Cout, nullptr, offs, HID, FFN_,
                      MAXR / 256, gemmBlocks, (int)blockIdx.x);
  else
    wconv_body(lds, w2, w2t, FFN_, HID, (int)blockIdx.x - gemmBlocks);
}

// ======== gemm2: TM=128, TRIPLE-buffered LDS, ONE barrier per K-tile ========
// Read buf t%3 while staging tile t+2 into buf (t+2)%3: the staged buffer's
// last reader (tile t-1) finished one full iteration + barrier ago -> WAR safe
// with a single end-of-iter barrier. Per-thread 6 gloads/iter -> gate vmcnt(6)
// when a stage was issued this iter, vmcnt(0) on the two drain iterations.
// LDS: 3 x [A 128x64 | B 256x64] = 3 x 48 KiB = 144 KiB. Same swizzle/maps as TM=128.

#define T3_STG_A(BASE, HALF, T) \
    gload_lds16(sA0 + (size_t)(HALF) * HOFF3 + (size_t)(T) * 64, (BASE) + (HALF) * 4096 + tid * 8)
#define T3_STG_B(BASE, HALF, T) do {                                        \
    ushort* _d = (BASE) + 8192 + (HALF) * 8192 + tid * 8;                   \
    gload_lds16(sB0 + (size_t)(HALF) * 32 * K3 + (size_t)(T) * 64, _d);     \
    gload_lds16(sB1 + (size_t)(HALF) * 32 * K3 + (size_t)(T) * 64, _d + 4096); \
  } while (0)
#define T3_LDA(BASE, MQ) do {                                               \
    _Pragma("unroll") for (int mm = 0; mm < 2; ++mm) {                      \
      const ushort* _p = (BASE) + (MQ) * 4096 + aoff + mm * 1024;           \
      af[mm][0] = *(const bf16x8*)(_p + ck0);                               \
      af[mm][1] = *(const bf16x8*)(_p + ck1);                               \
    } } while (0)
#define T3_LDB(BASE, NQ) do {                                               \
    _Pragma("unroll") for (int nn = 0; nn < 2; ++nn) {                      \
      const ushort* _p = (BASE) + 8192 + (NQ) * 8192 + boff + nn * 1024;    \
      bf[NQ][nn][0] = *(const bf16x8*)(_p + ck0);                           \
      bf[NQ][nn][1] = *(const bf16x8*)(_p + ck1);                           \
    } } while (0)
#define T3_MM(MQ, NQ) do {                                                  \
    __builtin_amdgcn_s_setprio(1);                                          \
    _Pragma("unroll") for (int mm = 0; mm < 2; ++mm)                        \
    _Pragma("unroll") for (int nn = 0; nn < 2; ++nn) {                      \
      acc[(MQ)*2+mm][(NQ)*2+nn] = __builtin_amdgcn_mfma_f32_16x16x32_bf16(  \
          af[mm][0], bf[NQ][nn][0], acc[(MQ)*2+mm][(NQ)*2+nn], 0, 0, 0);    \
      acc[(MQ)*2+mm][(NQ)*2+nn] = __builtin_amdgcn_mfma_f32_16x16x32_bf16(  \
          af[mm][1], bf[NQ][nn][1], acc[(MQ)*2+mm][(NQ)*2+nn], 0, 0, 0);    \
    }                                                                       \
    __builtin_amdgcn_s_setprio(0);                                          \
  } while (0)

__global__ __launch_bounds__(512, 2) void gemm2_tri_kernel(
    const ushort* __restrict__ A, const ushort* __restrict__ Bt,
    const float* __restrict__ bias, ushort* __restrict__ Cout,
    const float* __restrict__ slot_w, const int* __restrict__ offs, int gy)
{
  constexpr int K3 = FFN_;      // K = 8192
  constexpr int N3 = HID;       // N = 2048
  __shared__ ushort lds[73728]; // 144 KiB = 3 x 24576 ushorts

  const int tid = threadIdx.x;
  int nwg = gridDim.x;
  int wg = blockIdx.x;
  int cpx = nwg >> 3;
  wg = (wg & 7) * cpx + (wg >> 3);
  int cb = wg / gy;
  int rb = wg - cb * gy;

  int total = offs[NE];
  int row0 = rb * 128;
  if (row0 >= total) return;
  int e = 0;
#pragma unroll
  for (int i = 1; i < NE; ++i) e += (row0 >= offs[i]) ? 1 : 0;

  const ushort* Ag = A + (size_t)row0 * K3;
  const ushort* Bg = Bt + ((size_t)e * N3 + (size_t)cb * 256) * K3;

  const size_t HOFF3 = (size_t)32 * K3;         // A half offset = 32 rows
  const int pr0 = tid >> 3;
  const int pr1 = 64 + pr0;
  const int j0 = (tid & 7) ^ (pr0 & 7);
  const int j1 = (tid & 7) ^ (pr1 & 7);
  const int rA0 = ((pr0 >> 5) << 6) + (pr0 & 31);   // A map (TM=128)
  const int rB0 = ((pr0 >> 5) << 6) + (pr0 & 31);
  const int rB1 = ((pr1 >> 5) << 6) + (pr1 & 31);
  const ushort* sA0 = Ag + (size_t)rA0 * K3 + j0 * 8;
  const ushort* sB0 = Bg + (size_t)rB0 * K3 + j0 * 8;
  const ushort* sB1 = Bg + (size_t)rB1 * K3 + j1 * 8;

  const int lane = tid & 63;
  const int wid = tid >> 6;
  const int wr = wid >> 2, wc = wid & 3;
  const int lrow = lane & 15, g = lane >> 4, x7 = lrow & 7;
  const int ck0 = (g ^ x7) * 8;
  const int ck1 = ((4 + g) ^ x7) * 8;
  const int aoff = (wr * 32 + lrow) * 64;
  const int boff = (wc * 32 + lrow) * 64;

  f32x4 acc[4][4] = {};
  bf16x8 af[2][2], bf[2][2][2];

  constexpr int NT = K3 >> 6;   // 128 tiles

  // prologue: tiles 0,1 into buf0,buf1 (6 gloads each); wait tile0 (leave tile1's 6)
  {
    ushort* b0 = lds;
    ushort* b1 = lds + 24576;
    T3_STG_A(b0, 0, 0); T3_STG_A(b0, 1, 0); T3_STG_B(b0, 0, 0); T3_STG_B(b0, 1, 0);
    T3_STG_A(b1, 0, 1); T3_STG_A(b1, 1, 1); T3_STG_B(b1, 0, 1); T3_STG_B(b1, 1, 1);
  }
  VMW6();
  BAR(); SCB();

  int br = 0, bw = 2;
  for (int t = 0; t < NT; ++t) {
    ushort* Rb = lds + br * 24576;
    ushort* Wb = lds + bw * 24576;
    const bool stg = (t + 2 < NT);

    if (stg) { T3_STG_A(Wb, 0, t + 2); T3_STG_A(Wb, 1, t + 2); }
    T3_LDA(Rb, 0); T3_LDB(Rb, 0);
    T3_MM(0, 0);
    if (stg) T3_STG_B(Wb, 0, t + 2);
    T3_LDB(Rb, 1);
    T3_MM(0, 1);
    if (stg) T3_STG_B(Wb, 1, t + 2);
    T3_LDA(Rb, 1);
    T3_MM(1, 0);
    T3_MM(1, 1);
    if (stg) { VMW6(); } else { VMW0(); }   // gate: next tile fully landed
    BAR(); SCB();                           // single barrier per K-tile

    br = (br == 2) ? 0 : br + 1;
    bw = (bw == 2) ? 0 : bw + 1;
  }

  // epilogue (TM=128): EPI=1 (bias + slot_w scale)
  const int colb = cb * 256 + wc * 64;
  const int rowb = row0 + wr * 64;
  float bv[4];
#pragma unroll
  for (int n = 0; n < 4; ++n)
    bv[n] = bias[(size_t)e * N3 + colb + n * 16 + lrow];
#pragma unroll
  for (int m = 0; m < 4; ++m) {
    const int mq = m >> 1, mm = m & 1;
    const int gr = rowb + mq * 32 + mm * 16 + g * 4;
#pragma unroll
    for (int i = 0; i < 4; ++i) {
      const int grow = gr + i;
      float sw = slot_w[grow];
      ushort* crow = Cout + (size_t)grow * N3 + colb + lrow;
#pragma unroll
      for (int n = 0; n < 4; ++n) {
        float v = (acc[m][n][i] + bv[n]) * sw;
        crow[n * 16] = f2bf(v);
      }
    }
  }
}

// out = x + Y[slot0] + Y[slot1]
__global__ __launch_bounds__(256) void combine_kernel(
    const float* __restrict__ x, const ushort* __restrict__ Yp,
    const int* __restrict__ token_slot, float* __restrict__ out)
{
  int t = blockIdx.x;
  int s0 = token_slot[2 * t], s1 = token_slot[2 * t + 1];
  int c = threadIdx.x * 8;
  const float* xr = x + (size_t)t * HID + c;
  u16x8 y0 = *(const u16x8*)&Yp[(size_t)s0 * HID + c];
  u16x8 y1 = *(const u16x8*)&Yp[(size_t)s1 * HID + c];
  float4 xa = *(const float4*)xr;
  float4 xb = *(const float4*)(xr + 4);
  float4 oa, ob;
  oa.x = xa.x + bf2f(y0[0]) + bf2f(y1[0]);
  oa.y = xa.y + bf2f(y0[1]) + bf2f(y1[1]);
  oa.z = xa.z + bf2f(y0[2]) + bf2f(y1[2]);
  oa.w = xa.w + bf2f(y0[3]) + bf2f(y1[3]);
  ob.x = xb.x + bf2f(y0[4]) + bf2f(y1[4]);
  ob.y = xb.y + bf2f(y0[5]) + bf2f(y1[5]);
  ob.z = xb.z + bf2f(y0[6]) + bf2f(y1[6]);
  ob.w = xb.w + bf2f(y0[7]) + bf2f(y1[7]);
  float* orow = out + (size_t)t * HID + c;
  *(float4*)orow = oa;
  *(float4*)(orow + 4) = ob;
}

extern "C" void kernel_launch(void* const* d_in, const int* in_sizes, int n_in,
                              void* d_out, int out_size, void* d_ws, size_t ws_size,
                              hipStream_t stream)
{
  const float* x  = (const float*)d_in[0];
  const float* gw = (const float*)d_in[1];
  const float* w1 = (const float*)d_in[2];
  const float* b1 = (const float*)d_in[3];
  const float* w2 = (const float*)d_in[4];
  const float* b2 = (const float*)d_in[5];
  float* out = (float*)d_out;

  char* ws = (char*)d_ws;
  ushort* wT  = (ushort*)(ws + 0);            // w1t: [E][F][H] bf16, 268,435,456
  ushort* Hb  = (ushort*)(ws + 268435456);    // [MAXR][FFN] bf16: 301,989,888
  ushort* Xg  = (ushort*)(ws + 570425344);    // [MAXR][HID] bf16: 75,497,472
  ushort* Yp  = Xg;                           // Ypair overlays Xg
  char* sm = ws + 645922816;
  int*   slot_token = (int*)(sm);
  float* slot_w     = (float*)(sm + 73728);
  int*   token_slot = (int*)(sm + 147456);
  int*   topk_idx   = (int*)(sm + 212992);
  float* topk_w     = (float*)(sm + 278528);
  int*   counts     = (int*)(sm + 344064);
  int*   cursors    = (int*)(sm + 344096);
  int*   offs       = (int*)(sm + 344128);

  const size_t W2T_OFF = 646267136ULL;
  const bool fused = ws_size >= W2T_OFF + 268435456ULL;
  ushort* w2t = fused ? (ushort*)(ws + W2T_OFF) : wT;

  hipMemsetAsync(counts, 0, 64, stream);
  hipMemsetAsync(slot_token, 0xFF, MAXR * 4, stream);

  router_kernel<<<dim3(T_TOK / 4), dim3(256), 0, stream>>>(x, gw, topk_idx, topk_w, counts);
  offsets_kernel<<<dim3(1), dim3(64), 0, stream>>>(counts, offs);
  scatter_kernel<<<dim3(T_TOK / 256), dim3(256), 0, stream>>>(
      topk_idx, topk_w, offs, cursors, slot_token, slot_w, token_slot);

  gather_conv_kernel<<<dim3(4096 + MAXR / 2), dim3(512), 0, stream>>>(
      w1, wT, x, slot_token, Xg, 4096);

  if (fused) {
    gemm1_conv_kernel<<<dim3(2304 + 4096), dim3(512), 0, stream>>>(
        Xg, wT, b1, Hb, offs, w2, w2t, 2304);
  } else {
    gemm256_kernel<0, 256><<<dim3(2304), dim3(512), 0, stream>>>(
        Xg, wT, b1, Hb, nullptr, offs, HID, FFN_, MAXR / 256);
    wconvert_kernel<<<dim3(4096), dim3(512), 0, stream>>>(w2, wT, FFN_, HID);
  }

  // gemm2: TM=128 triple-buffered, 1 barrier / K-tile
  gemm2_tri_kernel<<<dim3((HID / 256) * (MAXR / 128)), dim3(512), 0, stream>>>(
      Hb, w2t, b2, Yp, slot_w, offs, MAXR / 128);

  combine_kernel<<<dim3(T_TOK), dim3(256), 0, stream>>>(x, Yp, token_slot, out);
}